// Round 2
// baseline (812.210 us; speedup 1.0000x reference)
//
#include <hip/hip_runtime.h>
#include <math.h>
#include <stdint.h>

#define S_SEQ 256
#define T_TOK 512
#define BERT 768
#define POSD 128
#define H1 1024
#define NC 6

#define CHUNK_T 128                 // tokens per block (4 blocks per sequence)
#define TILE_T 8                    // tokens per LDS tile
#define NTILES (CHUNK_T / TILE_T)   // 16
#define TILE_FLOATS (TILE_T * BERT) // 6144 floats = 24 KB

// CK-style direct global->LDS async copy, 16 B per lane.
// HW semantics: LDS dest = wave-uniform base + lane*16; global addr per-lane.
__device__ __forceinline__ void async_load16(const float* g, float* lds_uniform) {
    auto* l3 = reinterpret_cast<__attribute__((address_space(3))) uint32_t*>(
        reinterpret_cast<uintptr_t>(lds_uniform));
    auto* g1 = reinterpret_cast<const __attribute__((address_space(1))) uint32_t*>(
        reinterpret_cast<uintptr_t>(g));
    __builtin_amdgcn_global_load_lds(g1, l3, 16, 0, 0);
}

// ---------------------------------------------------------------------------
// Kernel 1: fused attention-logit + online-softmax weighted pooling.
// grid = 1024 (4 blocks per s), block = 256 (4 waves).
// Per tile of 8 tokens: wave w owns tokens {w*2, w*2+1}; per-wave online
// softmax; lane l owns embedding columns [l*12, l*12+12).
// One barrier per tile; next tile's DMA issued before compute (overlap).
// ---------------------------------------------------------------------------
__global__ __launch_bounds__(256, 3) void pool_kernel(
    const float* __restrict__ emb, const float* __restrict__ pos,
    const float* __restrict__ Wa, const float* __restrict__ ba,
    float* __restrict__ part_acc, float* __restrict__ part_ml)
{
    __shared__ float smem[2 * TILE_FLOATS + CHUNK_T + 8];   // ~49 KB
    float* plog = smem + 2 * TILE_FLOATS;   // [128] pos-part of logits
    float* wml  = plog + CHUNK_T;           // [8] per-wave m,l

    const int tid = threadIdx.x;
    const int w   = tid >> 6;
    const int l   = tid & 63;
    const int b   = blockIdx.x;
    const int s   = b >> 2;
    const int t0  = (b & 3) * CHUNK_T;

    const float* gbase = emb + ((size_t)s * T_TOK + t0) * BERT;

    // --- issue DMA for tile 0 into buf0 (6 x 1KB chunks per wave) ---
    #pragma unroll
    for (int c = 0; c < 6; ++c)
        async_load16(gbase + (w * 6 + c) * 256 + l * 4, smem + (w * 6 + c) * 256);

    // --- per-lane attention weights: 12 emb cols + 4 pos cols ---
    const float4* Wa4 = (const float4*)Wa;
    const float4 wa0 = Wa4[l * 3 + 0];
    const float4 wa1 = Wa4[l * 3 + 1];
    const float4 wa2 = Wa4[l * 3 + 2];
    const int l32 = l & 31;
    const float4 wp = Wa4[192 + l32];   // pos weights [768 + l32*4 ..)
    const float bav = ba[0];

    // --- phase 0: pos-part of logits, half-wave per token (16 iters) ---
    // Half-wave hw=tid>>5 computes tokens it*8+hw; wave w's halves (2w,2w+1)
    // produce exactly wave w's tokens -> per-wave locality, no barrier needed.
    const float4* pos4 = (const float4*)pos;
    const int hw = tid >> 5;
    for (int it = 0; it < CHUNK_T / 8; ++it) {
        const int tl = it * 8 + hw;
        const float4 p = pos4[((size_t)s * T_TOK + t0 + tl) * (POSD / 4) + l32];
        float d = p.x * wp.x + p.y * wp.y + p.z * wp.z + p.w * wp.w;
        #pragma unroll
        for (int off = 16; off >= 1; off >>= 1) d += __shfl_xor(d, off, 32);
        if (l32 == 0) plog[tl] = d + bav;
    }

    // --- per-wave online softmax state ---
    float m = -INFINITY, lsum = 0.f;
    float acc[12];
    #pragma unroll
    for (int j = 0; j < 12; ++j) acc[j] = 0.f;

    for (int tt = 0; tt < NTILES; ++tt) {
        float* cur = smem + (tt & 1) * TILE_FLOATS;
        __syncthreads();   // cur's DMA drained & visible; other buf consumed

        if (tt + 1 < NTILES) {   // issue next tile's DMA before computing
            float* nxt = smem + ((tt + 1) & 1) * TILE_FLOATS;
            const float* src = gbase + (size_t)(tt + 1) * TILE_FLOATS;
            #pragma unroll
            for (int c = 0; c < 6; ++c)
                async_load16(src + (w * 6 + c) * 256 + l * 4, nxt + (w * 6 + c) * 256);
        }

        // wave w's two tokens this tile
        const int i0 = tt * TILE_T + w * 2;
        const float4* r0 = (const float4*)(cur + (w * 2) * BERT);
        const float4* r1 = (const float4*)(cur + (w * 2 + 1) * BERT);
        const float4 a0 = r0[l * 3 + 0], a1 = r0[l * 3 + 1], a2 = r0[l * 3 + 2];
        const float4 b0 = r1[l * 3 + 0], b1 = r1[l * 3 + 1], b2 = r1[l * 3 + 2];

        float d0 = a0.x*wa0.x + a0.y*wa0.y + a0.z*wa0.z + a0.w*wa0.w
                 + a1.x*wa1.x + a1.y*wa1.y + a1.z*wa1.z + a1.w*wa1.w
                 + a2.x*wa2.x + a2.y*wa2.y + a2.z*wa2.z + a2.w*wa2.w;
        float d1 = b0.x*wa0.x + b0.y*wa0.y + b0.z*wa0.z + b0.w*wa0.w
                 + b1.x*wa1.x + b1.y*wa1.y + b1.z*wa1.z + b1.w*wa1.w
                 + b2.x*wa2.x + b2.y*wa2.y + b2.z*wa2.z + b2.w*wa2.w;
        #pragma unroll
        for (int off = 32; off >= 1; off >>= 1) {
            d0 += __shfl_xor(d0, off, 64);
            d1 += __shfl_xor(d1, off, 64);
        }

        const float lg0 = d0 + plog[i0];
        const float lg1 = d1 + plog[i0 + 1];
        const float mn = fmaxf(m, fmaxf(lg0, lg1));
        const float alpha = __expf(m - mn);       // first tile: exp(-inf)=0
        const float p0 = __expf(lg0 - mn);
        const float p1 = __expf(lg1 - mn);
        lsum = lsum * alpha + p0 + p1;
        m = mn;

        acc[0]  = fmaf(p0, a0.x, fmaf(p1, b0.x, acc[0]  * alpha));
        acc[1]  = fmaf(p0, a0.y, fmaf(p1, b0.y, acc[1]  * alpha));
        acc[2]  = fmaf(p0, a0.z, fmaf(p1, b0.z, acc[2]  * alpha));
        acc[3]  = fmaf(p0, a0.w, fmaf(p1, b0.w, acc[3]  * alpha));
        acc[4]  = fmaf(p0, a1.x, fmaf(p1, b1.x, acc[4]  * alpha));
        acc[5]  = fmaf(p0, a1.y, fmaf(p1, b1.y, acc[5]  * alpha));
        acc[6]  = fmaf(p0, a1.z, fmaf(p1, b1.z, acc[6]  * alpha));
        acc[7]  = fmaf(p0, a1.w, fmaf(p1, b1.w, acc[7]  * alpha));
        acc[8]  = fmaf(p0, a2.x, fmaf(p1, b2.x, acc[8]  * alpha));
        acc[9]  = fmaf(p0, a2.y, fmaf(p1, b2.y, acc[9]  * alpha));
        acc[10] = fmaf(p0, a2.z, fmaf(p1, b2.z, acc[10] * alpha));
        acc[11] = fmaf(p0, a2.w, fmaf(p1, b2.w, acc[11] * alpha));
    }

    // --- in-block merge of the 4 per-wave partials ---
    __syncthreads();            // all waves done reading tiles
    float* mg = smem;           // reuse: [4][768]
    #pragma unroll
    for (int j = 0; j < 12; ++j) mg[w * BERT + l * 12 + j] = acc[j];
    if (l == 0) { wml[w * 2] = m; wml[w * 2 + 1] = lsum; }
    __syncthreads();

    const float m0 = wml[0], l0 = wml[1], m1 = wml[2], l1 = wml[3];
    const float m2 = wml[4], l2 = wml[5], m3 = wml[6], l3 = wml[7];
    const float M  = fmaxf(fmaxf(m0, m1), fmaxf(m2, m3));
    const float e0 = __expf(m0 - M), e1 = __expf(m1 - M);
    const float e2 = __expf(m2 - M), e3 = __expf(m3 - M);
    const float lt = l0 * e0 + l1 * e1 + l2 * e2 + l3 * e3;
    #pragma unroll
    for (int k = 0; k < 3; ++k) {
        const int col = tid * 3 + k;
        const float v = e0 * mg[col] + e1 * mg[BERT + col]
                      + e2 * mg[2 * BERT + col] + e3 * mg[3 * BERT + col];
        part_acc[(size_t)b * BERT + col] = v;
    }
    if (tid == 0) { part_ml[b * 2] = M; part_ml[b * 2 + 1] = lt; }
}

// ---------------------------------------------------------------------------
// Kernel 2: merge the 4 partials per sequence, normalize, segment-sum.
// grid = 64, block = 256 (3 cols per thread).
// ---------------------------------------------------------------------------
__global__ void combine_segsum(
    const float* __restrict__ part_acc, const float* __restrict__ part_ml,
    const int* __restrict__ seg, float* __restrict__ vecs)
{
    const int c = blockIdx.x;
    const int tid = threadIdx.x;
    float v0 = 0.f, v1 = 0.f, v2 = 0.f;
    for (int s = 0; s < S_SEQ; ++s) {
        if (seg[s] != c) continue;
        const int p = s * 4;
        const float m0 = part_ml[(p+0)*2], l0 = part_ml[(p+0)*2+1];
        const float m1 = part_ml[(p+1)*2], l1 = part_ml[(p+1)*2+1];
        const float m2 = part_ml[(p+2)*2], l2 = part_ml[(p+2)*2+1];
        const float m3 = part_ml[(p+3)*2], l3 = part_ml[(p+3)*2+1];
        const float M  = fmaxf(fmaxf(m0, m1), fmaxf(m2, m3));
        const float e0 = __expf(m0 - M), e1 = __expf(m1 - M);
        const float e2 = __expf(m2 - M), e3 = __expf(m3 - M);
        const float inv = 1.0f / (l0*e0 + l1*e1 + l2*e2 + l3*e3);
        const int col = tid * 3;
        v0 += inv * (e0 * part_acc[(size_t)(p+0)*BERT + col]
                   + e1 * part_acc[(size_t)(p+1)*BERT + col]
                   + e2 * part_acc[(size_t)(p+2)*BERT + col]
                   + e3 * part_acc[(size_t)(p+3)*BERT + col]);
        v1 += inv * (e0 * part_acc[(size_t)(p+0)*BERT + col + 1]
                   + e1 * part_acc[(size_t)(p+1)*BERT + col + 1]
                   + e2 * part_acc[(size_t)(p+2)*BERT + col + 1]
                   + e3 * part_acc[(size_t)(p+3)*BERT + col + 1]);
        v2 += inv * (e0 * part_acc[(size_t)(p+0)*BERT + col + 2]
                   + e1 * part_acc[(size_t)(p+1)*BERT + col + 2]
                   + e2 * part_acc[(size_t)(p+2)*BERT + col + 2]
                   + e3 * part_acc[(size_t)(p+3)*BERT + col + 2]);
    }
    vecs[(size_t)c*BERT + tid*3 + 0] = v0;
    vecs[(size_t)c*BERT + tid*3 + 1] = v1;
    vecs[(size_t)c*BERT + tid*3 + 2] = v2;
}

// ---------------------------------------------------------------------------
// Kernel 3/4: out = leaky_relu(in @ W + b). 4 comments per block.
// grid = dim3(4, 16), block = 256. W is [K][1024] row-major.
// ---------------------------------------------------------------------------
__global__ void mlp_layer(
    const float* __restrict__ in, const float* __restrict__ W,
    const float* __restrict__ bias, float* __restrict__ out, int K)
{
    __shared__ float vf[4 * H1];
    const int tid = threadIdx.x;
    const int c0  = blockIdx.y * 4;
    const int j   = blockIdx.x * 256 + tid;
    for (int i = tid; i < 4 * K; i += 256) vf[i] = in[(size_t)c0 * K + i];
    __syncthreads();
    float a0 = 0.f, a1 = 0.f, a2 = 0.f, a3 = 0.f;
    #pragma unroll 4
    for (int k = 0; k < K; ++k) {
        const float wv = W[(size_t)k * H1 + j];
        a0 = fmaf(vf[k],         wv, a0);
        a1 = fmaf(vf[K + k],     wv, a1);
        a2 = fmaf(vf[2 * K + k], wv, a2);
        a3 = fmaf(vf[3 * K + k], wv, a3);
    }
    const float bj = bias[j];
    float r;
    r = a0 + bj; out[(size_t)(c0+0)*H1 + j] = r > 0.f ? r : 0.01f * r;
    r = a1 + bj; out[(size_t)(c0+1)*H1 + j] = r > 0.f ? r : 0.01f * r;
    r = a2 + bj; out[(size_t)(c0+2)*H1 + j] = r > 0.f ? r : 0.01f * r;
    r = a3 + bj; out[(size_t)(c0+3)*H1 + j] = r > 0.f ? r : 0.01f * r;
}

// ---------------------------------------------------------------------------
// Kernel 5: out = sigmoid(h @ W3 + b3). grid = 64, block = 256.
// ---------------------------------------------------------------------------
__global__ void mlp_out(
    const float* __restrict__ h, const float* __restrict__ W3,
    const float* __restrict__ b3, float* __restrict__ out)
{
    __shared__ float v[H1];
    __shared__ float red[NC][4];
    const int c = blockIdx.x;
    const int tid = threadIdx.x;
    const int wave = tid >> 6, lane = tid & 63;
    for (int i = tid; i < H1; i += 256) v[i] = h[(size_t)c * H1 + i];
    __syncthreads();
    float po[NC] = {0.f, 0.f, 0.f, 0.f, 0.f, 0.f};
    for (int k = tid; k < H1; k += 256) {
        const float hv = v[k];
        #pragma unroll
        for (int o = 0; o < NC; ++o) po[o] = fmaf(hv, W3[k * NC + o], po[o]);
    }
    #pragma unroll
    for (int o = 0; o < NC; ++o) {
        float d = po[o];
        #pragma unroll
        for (int off = 32; off >= 1; off >>= 1) d += __shfl_xor(d, off, 64);
        if (lane == 0) red[o][wave] = d;
    }
    __syncthreads();
    if (tid < NC) {
        const float sum = red[tid][0] + red[tid][1] + red[tid][2] + red[tid][3] + b3[tid];
        out[c * NC + tid] = 1.0f / (1.0f + __expf(-sum));
    }
}

// ---------------------------------------------------------------------------
extern "C" void kernel_launch(void* const* d_in, const int* in_sizes, int n_in,
                              void* d_out, int out_size, void* d_ws, size_t ws_size,
                              hipStream_t stream)
{
    const float* emb = (const float*)d_in[0];
    const float* pos = (const float*)d_in[1];
    const float* Wa  = (const float*)d_in[2];
    const float* ba  = (const float*)d_in[3];
    const float* W1  = (const float*)d_in[4];
    const float* b1  = (const float*)d_in[5];
    const float* W2  = (const float*)d_in[6];
    const float* b2  = (const float*)d_in[7];
    const float* W3  = (const float*)d_in[8];
    const float* b3  = (const float*)d_in[9];
    const int*   seg = (const int*)d_in[10];
    float* out = (float*)d_out;

    float* ws = (float*)d_ws;
    float* part_acc = ws;                        // 1024*768
    float* part_ml  = part_acc + 1024 * BERT;    // 1024*2
    float* vecs     = part_ml  + 1024 * 2;       // 64*768
    float* h1       = vecs     + 64 * BERT;      // 64*1024
    float* h2       = h1       + 64 * H1;        // 64*1024

    pool_kernel<<<1024, 256, 0, stream>>>(emb, pos, Wa, ba, part_acc, part_ml);
    combine_segsum<<<64, 256, 0, stream>>>(part_acc, part_ml, seg, vecs);
    mlp_layer<<<dim3(4, 16), 256, 0, stream>>>(vecs, W1, b1, h1, BERT);
    mlp_layer<<<dim3(4, 16), 256, 0, stream>>>(h1, W2, b2, h2, H1);
    mlp_out<<<64, 256, 0, stream>>>(h2, W3, b3, out);
}

// Round 3
// 679.209 us; speedup vs baseline: 1.1958x; 1.1958x over previous
//
#include <hip/hip_runtime.h>
#include <math.h>
#include <stdint.h>

#define S_SEQ 256
#define T_TOK 512
#define BERT 768
#define POSD 128
#define H1 1024
#define NC 6

#define CHUNK_T 128   // tokens per block (4 blocks per sequence)
#define WTOK 32       // tokens per wave (4 waves per block)

// ---------------------------------------------------------------------------
// Kernel 1: fused attention-logit + online-softmax weighted pooling.
// Register-resident: no LDS / no barriers in the main loop.
// grid = 1024 (4 blocks per s), block = 256 (4 waves).
// Wave w owns 32 consecutive tokens; lane l owns embedding columns
// {l*4..l*4+3, 256+l*4.., 512+l*4..} (12 cols) and pos columns {l*2, l*2+1}.
// Per token: 3x dwordx4 emb load + 1x dwordx2 pos load (fully coalesced),
// fused emb+pos logit dot -> wave shuffle-reduce -> online softmax update.
// ---------------------------------------------------------------------------
__global__ __launch_bounds__(256, 4) void pool_kernel(
    const float* __restrict__ emb, const float* __restrict__ pos,
    const float* __restrict__ Wa, const float* __restrict__ ba,
    float* __restrict__ part_acc, float* __restrict__ part_ml)
{
    __shared__ float mg[4 * BERT];   // 12 KB merge buffer
    __shared__ float wml[8];

    const int tid = threadIdx.x;
    const int w   = tid >> 6;
    const int l   = tid & 63;
    const int b   = blockIdx.x;
    const int s   = b >> 2;
    const int t0  = (b & 3) * CHUNK_T + w * WTOK;   // wave's first token

    // per-lane weights: 12 emb cols + 2 pos cols
    const float4* Wa4 = (const float4*)Wa;
    const float4 wa0 = Wa4[l];
    const float4 wa1 = Wa4[64 + l];
    const float4 wa2 = Wa4[128 + l];
    const float2 wp  = ((const float2*)(Wa + BERT))[l];
    const float  bav = ba[0];

    const float4* erow = (const float4*)(emb + ((size_t)s * T_TOK + t0) * BERT);
    const float2* prow = (const float2*)(pos + ((size_t)s * T_TOK + t0) * POSD);

    float m = -INFINITY, lsum = 0.f;
    float acc[12];
    #pragma unroll
    for (int j = 0; j < 12; ++j) acc[j] = 0.f;

    for (int i = 0; i < WTOK; i += 2) {
        const float4* r0 = erow + i * (BERT / 4);
        const float4* r1 = r0 + (BERT / 4);
        const float4 a0 = r0[l], a1 = r0[64 + l], a2 = r0[128 + l];
        const float4 b0 = r1[l], b1 = r1[64 + l], b2 = r1[128 + l];
        const float2 q0 = prow[i * (POSD / 2) + l];
        const float2 q1 = prow[(i + 1) * (POSD / 2) + l];

        float d0 = a0.x*wa0.x + a0.y*wa0.y + a0.z*wa0.z + a0.w*wa0.w
                 + a1.x*wa1.x + a1.y*wa1.y + a1.z*wa1.z + a1.w*wa1.w
                 + a2.x*wa2.x + a2.y*wa2.y + a2.z*wa2.z + a2.w*wa2.w
                 + q0.x*wp.x  + q0.y*wp.y;
        float d1 = b0.x*wa0.x + b0.y*wa0.y + b0.z*wa0.z + b0.w*wa0.w
                 + b1.x*wa1.x + b1.y*wa1.y + b1.z*wa1.z + b1.w*wa1.w
                 + b2.x*wa2.x + b2.y*wa2.y + b2.z*wa2.z + b2.w*wa2.w
                 + q1.x*wp.x  + q1.y*wp.y;
        #pragma unroll
        for (int off = 32; off >= 1; off >>= 1) {
            d0 += __shfl_xor(d0, off, 64);
            d1 += __shfl_xor(d1, off, 64);
        }

        const float lg0 = d0 + bav;
        const float lg1 = d1 + bav;
        const float mn  = fmaxf(m, fmaxf(lg0, lg1));
        const float alpha = __expf(m - mn);   // first iter: exp(-inf)=0
        const float p0 = __expf(lg0 - mn);
        const float p1 = __expf(lg1 - mn);
        lsum = lsum * alpha + p0 + p1;
        m = mn;

        acc[0]  = fmaf(p0, a0.x, fmaf(p1, b0.x, acc[0]  * alpha));
        acc[1]  = fmaf(p0, a0.y, fmaf(p1, b0.y, acc[1]  * alpha));
        acc[2]  = fmaf(p0, a0.z, fmaf(p1, b0.z, acc[2]  * alpha));
        acc[3]  = fmaf(p0, a0.w, fmaf(p1, b0.w, acc[3]  * alpha));
        acc[4]  = fmaf(p0, a1.x, fmaf(p1, b1.x, acc[4]  * alpha));
        acc[5]  = fmaf(p0, a1.y, fmaf(p1, b1.y, acc[5]  * alpha));
        acc[6]  = fmaf(p0, a1.z, fmaf(p1, b1.z, acc[6]  * alpha));
        acc[7]  = fmaf(p0, a1.w, fmaf(p1, b1.w, acc[7]  * alpha));
        acc[8]  = fmaf(p0, a2.x, fmaf(p1, b2.x, acc[8]  * alpha));
        acc[9]  = fmaf(p0, a2.y, fmaf(p1, b2.y, acc[9]  * alpha));
        acc[10] = fmaf(p0, a2.z, fmaf(p1, b2.z, acc[10] * alpha));
        acc[11] = fmaf(p0, a2.w, fmaf(p1, b2.w, acc[11] * alpha));
    }

    // --- in-block merge of the 4 per-wave partials (by absolute column) ---
    #pragma unroll
    for (int j = 0; j < 4; ++j) {
        mg[w * BERT +       l * 4 + j] = acc[j];
        mg[w * BERT + 256 + l * 4 + j] = acc[4 + j];
        mg[w * BERT + 512 + l * 4 + j] = acc[8 + j];
    }
    if (l == 0) { wml[w * 2] = m; wml[w * 2 + 1] = lsum; }
    __syncthreads();

    const float m0 = wml[0], l0 = wml[1], m1 = wml[2], l1 = wml[3];
    const float m2 = wml[4], l2 = wml[5], m3 = wml[6], l3 = wml[7];
    const float M  = fmaxf(fmaxf(m0, m1), fmaxf(m2, m3));
    const float e0 = __expf(m0 - M), e1 = __expf(m1 - M);
    const float e2 = __expf(m2 - M), e3 = __expf(m3 - M);
    const float lt = l0 * e0 + l1 * e1 + l2 * e2 + l3 * e3;
    #pragma unroll
    for (int k = 0; k < 3; ++k) {
        const int col = tid * 3 + k;
        part_acc[(size_t)b * BERT + col] =
              e0 * mg[col] + e1 * mg[BERT + col]
            + e2 * mg[2 * BERT + col] + e3 * mg[3 * BERT + col];
    }
    if (tid == 0) { part_ml[b * 2] = M; part_ml[b * 2 + 1] = lt; }
}

// ---------------------------------------------------------------------------
// Kernel 2: merge the 4 partials per sequence, normalize, segment-sum.
// grid = 64, block = 256 (3 cols per thread).
// ---------------------------------------------------------------------------
__global__ void combine_segsum(
    const float* __restrict__ part_acc, const float* __restrict__ part_ml,
    const int* __restrict__ seg, float* __restrict__ vecs)
{
    const int c = blockIdx.x;
    const int tid = threadIdx.x;
    float v0 = 0.f, v1 = 0.f, v2 = 0.f;
    for (int s = 0; s < S_SEQ; ++s) {
        if (seg[s] != c) continue;
        const int p = s * 4;
        const float m0 = part_ml[(p+0)*2], l0 = part_ml[(p+0)*2+1];
        const float m1 = part_ml[(p+1)*2], l1 = part_ml[(p+1)*2+1];
        const float m2 = part_ml[(p+2)*2], l2 = part_ml[(p+2)*2+1];
        const float m3 = part_ml[(p+3)*2], l3 = part_ml[(p+3)*2+1];
        const float M  = fmaxf(fmaxf(m0, m1), fmaxf(m2, m3));
        const float e0 = __expf(m0 - M), e1 = __expf(m1 - M);
        const float e2 = __expf(m2 - M), e3 = __expf(m3 - M);
        const float inv = 1.0f / (l0*e0 + l1*e1 + l2*e2 + l3*e3);
        const int col = tid * 3;
        v0 += inv * (e0 * part_acc[(size_t)(p+0)*BERT + col]
                   + e1 * part_acc[(size_t)(p+1)*BERT + col]
                   + e2 * part_acc[(size_t)(p+2)*BERT + col]
                   + e3 * part_acc[(size_t)(p+3)*BERT + col]);
        v1 += inv * (e0 * part_acc[(size_t)(p+0)*BERT + col + 1]
                   + e1 * part_acc[(size_t)(p+1)*BERT + col + 1]
                   + e2 * part_acc[(size_t)(p+2)*BERT + col + 1]
                   + e3 * part_acc[(size_t)(p+3)*BERT + col + 1]);
        v2 += inv * (e0 * part_acc[(size_t)(p+0)*BERT + col + 2]
                   + e1 * part_acc[(size_t)(p+1)*BERT + col + 2]
                   + e2 * part_acc[(size_t)(p+2)*BERT + col + 2]
                   + e3 * part_acc[(size_t)(p+3)*BERT + col + 2]);
    }
    vecs[(size_t)c*BERT + tid*3 + 0] = v0;
    vecs[(size_t)c*BERT + tid*3 + 1] = v1;
    vecs[(size_t)c*BERT + tid*3 + 2] = v2;
}

// ---------------------------------------------------------------------------
// Kernel 3/4: dense layer out = leaky_relu(in @ W + b), W is [K][1024].
// grid = dim3(4, 64) (j-tile, comment), block = 256 -> 256 blocks (full CU
// coverage; W stays L2/L3-hot across comment blocks).
// ---------------------------------------------------------------------------
__global__ void mlp_layer(
    const float* __restrict__ in, const float* __restrict__ W,
    const float* __restrict__ bias, float* __restrict__ out, int K)
{
    __shared__ float v[H1];   // input row (K <= 1024)
    const int c  = blockIdx.y;
    const int tid = threadIdx.x;
    const int j  = blockIdx.x * 256 + tid;
    for (int i = tid; i < K; i += 256) v[i] = in[(size_t)c*K + i];
    __syncthreads();
    float a0 = 0.f, a1 = 0.f, a2 = 0.f, a3 = 0.f;
    #pragma unroll 4
    for (int k = 0; k < K; k += 4) {
        a0 = fmaf(v[k  ], W[(size_t)(k  )*H1 + j], a0);
        a1 = fmaf(v[k+1], W[(size_t)(k+1)*H1 + j], a1);
        a2 = fmaf(v[k+2], W[(size_t)(k+2)*H1 + j], a2);
        a3 = fmaf(v[k+3], W[(size_t)(k+3)*H1 + j], a3);
    }
    const float acc = bias[j] + ((a0 + a1) + (a2 + a3));
    out[(size_t)c*H1 + j] = acc > 0.f ? acc : 0.01f * acc;
}

// ---------------------------------------------------------------------------
// Kernel 5: out = sigmoid(h @ W3 + b3). grid = 64, block = 256.
// ---------------------------------------------------------------------------
__global__ void mlp_out(
    const float* __restrict__ h, const float* __restrict__ W3,
    const float* __restrict__ b3, float* __restrict__ out)
{
    __shared__ float v[H1];
    __shared__ float red[NC][4];
    const int c = blockIdx.x;
    const int tid = threadIdx.x;
    const int wave = tid >> 6, lane = tid & 63;
    for (int i = tid; i < H1; i += 256) v[i] = h[(size_t)c * H1 + i];
    __syncthreads();
    float po[NC] = {0.f, 0.f, 0.f, 0.f, 0.f, 0.f};
    for (int k = tid; k < H1; k += 256) {
        const float hv = v[k];
        #pragma unroll
        for (int o = 0; o < NC; ++o) po[o] = fmaf(hv, W3[k * NC + o], po[o]);
    }
    #pragma unroll
    for (int o = 0; o < NC; ++o) {
        float d = po[o];
        #pragma unroll
        for (int off = 32; off >= 1; off >>= 1) d += __shfl_xor(d, off, 64);
        if (lane == 0) red[o][wave] = d;
    }
    __syncthreads();
    if (tid < NC) {
        const float sum = red[tid][0] + red[tid][1] + red[tid][2] + red[tid][3] + b3[tid];
        out[c * NC + tid] = 1.0f / (1.0f + __expf(-sum));
    }
}

// ---------------------------------------------------------------------------
extern "C" void kernel_launch(void* const* d_in, const int* in_sizes, int n_in,
                              void* d_out, int out_size, void* d_ws, size_t ws_size,
                              hipStream_t stream)
{
    const float* emb = (const float*)d_in[0];
    const float* pos = (const float*)d_in[1];
    const float* Wa  = (const float*)d_in[2];
    const float* ba  = (const float*)d_in[3];
    const float* W1  = (const float*)d_in[4];
    const float* b1  = (const float*)d_in[5];
    const float* W2  = (const float*)d_in[6];
    const float* b2  = (const float*)d_in[7];
    const float* W3  = (const float*)d_in[8];
    const float* b3  = (const float*)d_in[9];
    const int*   seg = (const int*)d_in[10];
    float* out = (float*)d_out;

    float* ws = (float*)d_ws;
    float* part_acc = ws;                        // 1024*768
    float* part_ml  = part_acc + 1024 * BERT;    // 1024*2
    float* vecs     = part_ml  + 1024 * 2;       // 64*768
    float* h1       = vecs     + 64 * BERT;      // 64*1024
    float* h2       = h1       + 64 * H1;        // 64*1024

    pool_kernel<<<1024, 256, 0, stream>>>(emb, pos, Wa, ba, part_acc, part_ml);
    combine_segsum<<<64, 256, 0, stream>>>(part_acc, part_ml, seg, vecs);
    mlp_layer<<<dim3(4, 64), 256, 0, stream>>>(vecs, W1, b1, h1, BERT);
    mlp_layer<<<dim3(4, 64), 256, 0, stream>>>(h1, W2, b2, h2, H1);
    mlp_out<<<64, 256, 0, stream>>>(h2, W3, b3, out);
}